// Round 5
// baseline (151.128 us; speedup 1.0000x reference)
//
#include <hip/hip_runtime.h>
#include <math.h>

#define BB 16
#define TT 2048
#define FF 512
#define POOL_BLOCKS 8192          // 512 blocks/batch x 16 batches, 4 rows per block

typedef float v4f __attribute__((ext_vector_type(4)));

// K1: wt[b,t] = sigmoid(dot(x[b,t,:], w) + bias). One wave (64 lanes) per row.
__global__ __launch_bounds__(256) void wt_kernel(const float* __restrict__ x,
                                                 const float* __restrict__ w,
                                                 const float* __restrict__ bias,
                                                 float* __restrict__ wt) {
    int gid  = blockIdx.x * 256 + threadIdx.x;
    int row  = gid >> 6;    // [0, B*T)
    int lane = gid & 63;
    const float* xr = x + (size_t)row * FF + lane * 8;
    const float* wr = w + lane * 8;
    float4 a0 = *(const float4*)xr;
    float4 a1 = *(const float4*)(xr + 4);
    float4 w0 = *(const float4*)wr;
    float4 w1 = *(const float4*)(wr + 4);
    float s = a0.x * w0.x + a0.y * w0.y + a0.z * w0.z + a0.w * w0.w
            + a1.x * w1.x + a1.y * w1.y + a1.z * w1.z + a1.w * w1.w;
#pragma unroll
    for (int off = 32; off > 0; off >>= 1) s += __shfl_xor(s, off, 64);
    if (lane == 0) {
        float z = s + bias[0];
        wt[row] = 1.0f / (1.0f + expf(-z));
    }
}

// K2: fused seg-on-the-fly + pool + mask.
// blk 0: mask. blk 1..8192: pool, block k-1 -> batch b=(k-1)>>9, rows j0..j0+3, j0=((k-1)&511)*4.
// Valleys are strict local minima -> never adjacent -> counts <= 1024, so j0>=1024 blocks
// are pure zero-writers. Active blocks rebuild the segment table from wt (L2-hot, 8KB/row):
// LDS valley flags + wave scan + binary-search selection of the j-th valley.
__global__ __launch_bounds__(256) void pool_mask_kernel(const float* __restrict__ x,
                                                        const float* __restrict__ wt,
                                                        const int* __restrict__ seq_len,
                                                        float* __restrict__ out,
                                                        float* __restrict__ mask_out) {
    int blk = blockIdx.x;
    int tid = threadIdx.x;

    if (blk == 0) {
        // ---- mask block: recompute per-batch valley counts, then write new_mask ----
        __shared__ int cnt16[BB];
        __shared__ int nl16[BB];
        if (tid < BB) cnt16[tid] = 0;
        __syncthreads();
        int br = tid >> 4;                 // 16 threads per batch
        int t0 = (tid & 15) * 128;
        const float* wr = wt + br * TT;
        int c = 0;
        for (int k = 0; k < 128; ++k) {
            int t = t0 + k;
            if (t > 0 && t < TT - 1) {
                float cv = wr[t];
                if (cv < wr[t - 1] && cv < wr[t + 1]) ++c;
            }
        }
        atomicAdd(&cnt16[br], c);
        __syncthreads();
        int maxc = 0;
#pragma unroll
        for (int i = 0; i < BB; ++i) maxc = max(maxc, cnt16[i] + 1);
        if (tid < BB) {
            int len_b = min(seq_len[tid], TT);
            int len0  = min(seq_len[0], TT);
            nl16[tid] = (int)((float)len_b / (float)len0 * (float)maxc);
        }
        __syncthreads();
        for (int i = tid; i < BB * TT; i += 256) {
            int bb = i >> 11, t = i & (TT - 1);
            mask_out[i] = (t < nl16[bb]) ? 1.0f : 0.0f;
        }
        return;
    }

    int pb   = blk - 1;
    int b    = pb >> 9;
    int j0   = (pb & 511) * 4;
    int lane = tid & 63;
    int wv   = tid >> 6;
    int row  = b * TT + j0 + wv;          // this wave's output row
    float* orow = out + (size_t)row * FF + lane * 8;
    v4f zero = (v4f)(0.f);

    if (j0 >= 1024) {                     // counts <= 1024 always -> zero rows
        __builtin_nontemporal_store(zero, (v4f*)orow);
        __builtin_nontemporal_store(zero, (v4f*)(orow + 4));
        return;
    }

    __shared__ float sw[TT];              // wt row
    __shared__ int   sflag[256];          // 8-bit valley flags per thread
    __shared__ int   sexcl[256];          // exclusive scan of flag popcounts
    __shared__ int   swsum[4];            // per-wave totals
    const float* wrow = wt + b * TT;
    ((v4f*)sw)[tid]       = ((const v4f*)wrow)[tid];
    ((v4f*)sw)[tid + 256] = ((const v4f*)wrow)[tid + 256];
    __syncthreads();

    unsigned int flags = 0;
    int base = tid * 8;
#pragma unroll
    for (int k = 0; k < 8; ++k) {
        int t = base + k;
        float c = sw[t];
        bool v = (t > 0) && (t < TT - 1) && (c < sw[t - 1]) && (c < sw[t + 1]);
        if (v) flags |= (1u << k);
    }
    int cnt = __popc(flags);
    sflag[tid] = (int)flags;
    int inc = cnt;
#pragma unroll
    for (int off = 1; off < 64; off <<= 1) {
        int y = __shfl_up(inc, off, 64);
        if (lane >= off) inc += y;
    }
    if (lane == 63) swsum[wv] = inc;
    sexcl[tid] = inc - cnt;               // intra-wave exclusive
    __syncthreads();
    int woff = 0;
    for (int i = 0; i < 4; ++i) if (i < wv) woff += swsum[i];
    int myexcl = sexcl[tid] + woff;
    __syncthreads();                      // everyone done reading old sexcl/swsum
    sexcl[tid] = myexcl;
    __syncthreads();
    int Vtot = sexcl[255] + __popc((unsigned)sflag[255]);   // number of valleys

    int j = j0 + wv;
    v4f acc0 = (v4f)(0.f);
    v4f acc1 = (v4f)(0.f);
    bool active = (j <= Vtot);            // counts = Vtot + 1
    if (active) {
        // nth_valley(rho): position of the rho-th (0-based) valley
        auto nth_valley = [&](int rho) -> int {
            int lo = 0, hi = 255;
            while (lo < hi) {
                int mid = (lo + hi + 1) >> 1;
                if (sexcl[mid] <= rho) lo = mid; else hi = mid - 1;
            }
            unsigned int f = (unsigned)sflag[lo];
            int r = rho - sexcl[lo];
            while (r--) f &= f - 1;
            return lo * 8 + (__ffs(f) - 1);
        };
        int s = (j == 0) ? 0 : nth_valley(j - 1);
        int e = (j < Vtot) ? nth_valley(j) + 2 : TT;
        const float* xb = x + (size_t)b * TT * FF + lane * 8;
        float den = 0.f;
        for (int t = s; t < e; ++t) {
            float wvv = sw[t];
            const v4f* p = (const v4f*)(xb + (size_t)t * FF);
            v4f v0 = p[0], v1 = p[1];
            acc0 += wvv * v0;
            acc1 += wvv * v1;
            den += wvv;
        }
        float invd = 1.0f / fmaxf(den, 1e-6f);
        acc0 *= invd; acc1 *= invd;
    }
    __builtin_nontemporal_store(acc0, (v4f*)orow);
    __builtin_nontemporal_store(acc1, (v4f*)(orow + 4));
}

extern "C" void kernel_launch(void* const* d_in, const int* in_sizes, int n_in,
                              void* d_out, int out_size, void* d_ws, size_t ws_size,
                              hipStream_t stream) {
    const float* x       = (const float*)d_in[0];
    const float* w_aggr  = (const float*)d_in[1];
    const float* b_aggr  = (const float*)d_in[2];
    const int*   seq_len = (const int*)d_in[3];

    float* pooled = (float*)d_out;
    float* mask   = (float*)d_out + (size_t)BB * TT * FF;

    float* wt = (float*)d_ws;             // only ws use: [B*T] f32

    wt_kernel<<<(BB * TT) / 4, 256, 0, stream>>>(x, w_aggr, b_aggr, wt);
    pool_mask_kernel<<<POOL_BLOCKS + 1, 256, 0, stream>>>(x, wt, seq_len, pooled, mask);
}

// Round 6
// 125.479 us; speedup vs baseline: 1.2044x; 1.2044x over previous
//
#include <hip/hip_runtime.h>
#include <math.h>

#define BB 16
#define TT 2048
#define FF 512

#define ACTIVE_BLOCKS 4096   // 256 blocks/batch x 16, 4 waves/block, 1 wave per row j<1024
#define ZERO_BLOCKS   1024   // rows j in [1024,2048): always zero (counts <= 1024), 16 rows/block
#define MASK_BLOCKS   32

typedef float v4f __attribute__((ext_vector_type(4)));

// K1: wt[b,t] = sigmoid(dot(x[b,t,:], w) + bias). One wave (64 lanes) per row.
__global__ __launch_bounds__(256) void wt_kernel(const float* __restrict__ x,
                                                 const float* __restrict__ w,
                                                 const float* __restrict__ bias,
                                                 float* __restrict__ wt) {
    int gid  = blockIdx.x * 256 + threadIdx.x;
    int row  = gid >> 6;    // [0, B*T)
    int lane = gid & 63;
    const float* xr = x + (size_t)row * FF + lane * 8;
    const float* wr = w + lane * 8;
    float4 a0 = *(const float4*)xr;
    float4 a1 = *(const float4*)(xr + 4);
    float4 w0 = *(const float4*)wr;
    float4 w1 = *(const float4*)(wr + 4);
    float s = a0.x * w0.x + a0.y * w0.y + a0.z * w0.z + a0.w * w0.w
            + a1.x * w1.x + a1.y * w1.y + a1.z * w1.z + a1.w * w1.w;
#pragma unroll
    for (int off = 32; off > 0; off >>= 1) s += __shfl_xor(s, off, 64);
    if (lane == 0) {
        float z = s + bias[0];
        wt[row] = 1.0f / (1.0f + expf(-z));
    }
}

// K2: one WAVE per batch. Valley detect + wave-scan compaction, no barriers.
// starts = [0, v1, ..., vk]; ends = [v1+2, ..., vk+2, T]; counts = k+1 (<= 1024).
__global__ __launch_bounds__(64) void seg_kernel(const float* __restrict__ wt,
                                                 int* __restrict__ starts,
                                                 int* __restrict__ ends,
                                                 int* __restrict__ counts) {
    int b    = blockIdx.x;
    int lane = threadIdx.x;              // 0..63, 32 consecutive positions each
    const float* wrow = wt + b * TT;
    float v[32];
    const float4* p = (const float4*)(wrow + lane * 32);
#pragma unroll
    for (int k = 0; k < 8; ++k) {
        float4 f = p[k];
        v[4*k] = f.x; v[4*k+1] = f.y; v[4*k+2] = f.z; v[4*k+3] = f.w;
    }
    float left  = __shfl_up(v[31], 1, 64);
    float right = __shfl_down(v[0], 1, 64);
    unsigned int flags = 0;
#pragma unroll
    for (int k = 0; k < 32; ++k) {
        int t = lane * 32 + k;
        float prev = (k == 0)  ? left  : v[k - 1];
        float next = (k == 31) ? right : v[k + 1];
        bool val = (t > 0) && (t < TT - 1) && (v[k] < prev) && (v[k] < next);
        if (val) flags |= (1u << k);
    }
    int cnt = __popc(flags);
    int inc = cnt;
#pragma unroll
    for (int off = 1; off < 64; off <<= 1) {
        int y = __shfl_up(inc, off, 64);
        if (lane >= off) inc += y;
    }
    int total = __shfl(inc, 63, 64);
    int r = inc - cnt;
    int* sb = starts + b * TT;
    int* eb = ends + b * TT;
    unsigned int f = flags;
    while (f) {
        int k = __ffs(f) - 1;
        f &= f - 1;
        int t = lane * 32 + k;
        sb[r + 1] = t;
        eb[r] = t + 2;                   // t <= 2046 -> t+2 <= TT
        ++r;
    }
    if (lane == 0) {
        sb[0] = 0;
        eb[total] = TT;
        counts[b] = total + 1;
    }
}

// K3: partitioned pool + zero + mask.
//  [0, ACTIVE_BLOCKS): rows j<1024, 1 wave/row, unroll-4 clamped segment loop.
//  [ACTIVE_BLOCKS, +ZERO_BLOCKS): rows j>=1024, pure NT zero stores (16 rows/block).
//  [.., +MASK_BLOCKS): new_mask from counts[].
__global__ __launch_bounds__(256) void pool_kernel(const float* __restrict__ x,
                                                   const float* __restrict__ wt,
                                                   const int* __restrict__ starts,
                                                   const int* __restrict__ ends,
                                                   const int* __restrict__ counts,
                                                   const int* __restrict__ seq_len,
                                                   float* __restrict__ out,
                                                   float* __restrict__ mask_out) {
    int blk = blockIdx.x;
    int tid = threadIdx.x;
    v4f zero = (v4f)(0.f);

    if (blk >= ACTIVE_BLOCKS + ZERO_BLOCKS) {
        // ---- mask ----
        int idx = (blk - ACTIVE_BLOCKS - ZERO_BLOCKS) * 256 + tid;  // [0, 8192)
        int maxc = 0;
#pragma unroll
        for (int i = 0; i < BB; ++i) maxc = max(maxc, counts[i]);
        float len0 = (float)min(seq_len[0], TT);
#pragma unroll
        for (int r = 0; r < 4; ++r) {
            int i = idx + r * 8192;       // [0, B*T)
            int b = i >> 11, t = i & (TT - 1);
            int nl = (int)((float)min(seq_len[b], TT) / len0 * (float)maxc);
            mask_out[i] = (t < nl) ? 1.0f : 0.0f;
        }
        return;
    }

    if (blk >= ACTIVE_BLOCKS) {
        // ---- zero region: rows j in [1024, 2048), 16 rows per block ----
        int zb = blk - ACTIVE_BLOCKS;     // [0, 1024)
        int b  = zb >> 6;                 // 64 blocks per batch
        int j0 = 1024 + (zb & 63) * 16;
        float* base = out + ((size_t)(b * TT + j0) * FF);
        // 16 rows x 512 f = 8192 floats; 256 threads x 8 floats (2 x v4f)
        v4f* dst = (v4f*)base + tid * 2;
        __builtin_nontemporal_store(zero, dst);
        __builtin_nontemporal_store(zero, dst + 1);
        return;
    }

    // ---- active pool: 4 waves/block, 1 wave per row, j in [0, 1024) ----
    int b    = blk >> 8;                  // 256 blocks per batch
    int wv   = tid >> 6;
    int lane = tid & 63;
    int j    = (blk & 255) * 4 + wv;
    int row  = b * TT + j;
    float* orow = out + (size_t)row * FF + lane * 8;

    v4f acc0 = (v4f)(0.f);
    v4f acc1 = (v4f)(0.f);
    if (j < counts[b]) {
        int s = __builtin_amdgcn_readfirstlane(starts[row]);
        int e = __builtin_amdgcn_readfirstlane(ends[row]);
        const float* xb   = x + (size_t)b * TT * FF + lane * 8;
        const float* wrow = wt + b * TT;
        float den = 0.f;
        for (int t = s; t < e; t += 4) {
            int i1 = (t + 1 < e) ? t + 1 : t;
            int i2 = (t + 2 < e) ? t + 2 : t;
            int i3 = (t + 3 < e) ? t + 3 : t;
            float w0 = wrow[t];
            float w1 = (t + 1 < e) ? wrow[i1] : 0.f;
            float w2 = (t + 2 < e) ? wrow[i2] : 0.f;
            float w3 = (t + 3 < e) ? wrow[i3] : 0.f;
            const v4f* p0 = (const v4f*)(xb + (size_t)t  * FF);
            const v4f* p1 = (const v4f*)(xb + (size_t)i1 * FF);
            const v4f* p2 = (const v4f*)(xb + (size_t)i2 * FF);
            const v4f* p3 = (const v4f*)(xb + (size_t)i3 * FF);
            v4f v00 = p0[0], v01 = p0[1];
            v4f v10 = p1[0], v11 = p1[1];
            v4f v20 = p2[0], v21 = p2[1];
            v4f v30 = p3[0], v31 = p3[1];
            acc0 += w0 * v00; acc1 += w0 * v01;
            acc0 += w1 * v10; acc1 += w1 * v11;
            acc0 += w2 * v20; acc1 += w2 * v21;
            acc0 += w3 * v30; acc1 += w3 * v31;
            den += w0 + w1 + w2 + w3;
        }
        float inv = 1.0f / fmaxf(den, 1e-6f);
        acc0 *= inv; acc1 *= inv;
    }
    __builtin_nontemporal_store(acc0, (v4f*)orow);
    __builtin_nontemporal_store(acc1, (v4f*)(orow + 4));
}

extern "C" void kernel_launch(void* const* d_in, const int* in_sizes, int n_in,
                              void* d_out, int out_size, void* d_ws, size_t ws_size,
                              hipStream_t stream) {
    const float* x       = (const float*)d_in[0];
    const float* w_aggr  = (const float*)d_in[1];
    const float* b_aggr  = (const float*)d_in[2];
    const int*   seq_len = (const int*)d_in[3];

    float* pooled = (float*)d_out;
    float* mask   = (float*)d_out + (size_t)BB * TT * FF;

    float* wt    = (float*)d_ws;
    int* starts  = (int*)((char*)d_ws + (size_t)BB * TT * 4);
    int* ends    = starts + BB * TT;
    int* counts  = ends + BB * TT;

    wt_kernel<<<(BB * TT) / 4, 256, 0, stream>>>(x, w_aggr, b_aggr, wt);
    seg_kernel<<<BB, 64, 0, stream>>>(wt, starts, ends, counts);
    pool_kernel<<<ACTIVE_BLOCKS + ZERO_BLOCKS + MASK_BLOCKS, 256, 0, stream>>>(
        x, wt, starts, ends, counts, seq_len, pooled, mask);
}